// Round 9
// baseline (833.399 us; speedup 1.0000x reference)
//
#include <hip/hip_runtime.h>
#include <math.h>

#define V 23
#define HH 256
#define BB 512
#define LL 1024
#define NOUT 46  // 2V

typedef float f32x2 __attribute__((ext_vector_type(2)));
typedef float f32x4 __attribute__((ext_vector_type(4)));

// Multiplicative inverses mod 23, packed 5 bits/entry into two u64 scalars
// (entries 0..11 in T0, 12..22 in T1) so the inverse lookup is pure SALU.
constexpr unsigned long long packInv(int lo) {
    const int inv[23] = {0,1,12,8,6,14,4,10,3,18,7,21,2,16,5,20,13,19,9,17,15,11,22};
    unsigned long long t = 0;
    for (int i = 0; i < 12; ++i) {
        int idx = lo + i;
        if (idx < 23) t |= (unsigned long long)inv[idx] << (5 * i);
    }
    return t;
}
constexpr unsigned long long INV_T0 = packInv(0);
constexpr unsigned long long INV_T1 = packInv(12);

// VALU max-reduce step via DPP (no DS pipe, ~8 cy vs ~120 cy ds_swizzle)
#define DPPMAX(v, ctrl, rmask)                                                  \
    do {                                                                        \
        unsigned _t = (unsigned)__builtin_amdgcn_update_dpp(                    \
            (int)(v), (int)(v), (ctrl), (rmask), 0xF, false);                   \
        (v) = ((v) > _t) ? (v) : _t;                                            \
    } while (0)

// R12: R7 base (674us best; R11's setprio/peel/rfl reverted — +21us). Model
// from R0..R11: wall/step = VALU issue (~1:1, per R2<->R3's 77us/96-instr) +
// EXPOSED DS-trip latency (VALUBusy 44% => both resident blocks stall
// together; chain DS trips are not hidden). The sV round-trip is the one
// chain DS-trip replaceable at SUB-1:1 issue cost: v_readlane -> SGPR pair
// feeding v_pk_fma_f32 (VOP3P allows one scalar src). vs R7: +64 readlane,
// -16 ds_read_b128 (+48 instr, +96cy) for -~150cy chain latency and 64 fewer
// b128 bursts in the DS queue ahead of the other block's critical reads.
// (R2 tried readlane with SCALAR fmac: +128 instr — the pk pairing is what
// flips the trade.) w*v operand swap is IEEE-commutative -> bit-exact.
__global__ __launch_bounds__(256, 2)
void daf_kernel(const int* __restrict__ xtok,
                const float* __restrict__ W1,
                const float* __restrict__ b1,
                const float* __restrict__ W2,
                const float* __restrict__ b2,
                float* __restrict__ out)
{
    __shared__ float sW1[V * HH];     // W1 rows for the h-update
    __shared__ float sP[2][4][64];    // partials [parity][wave][lane], dbl-buffered,
                                      // conflict-free both directions (R5)
    __shared__ int   sTok[LL];
    __shared__ int   sK[LL];          // emitted symbols; flushed to global at end

    const int tid = threadIdx.x;
    const int w   = tid >> 6;
    const int l   = tid & 63;
    const int b   = blockIdx.x;

    for (int i = tid; i < V * HH; i += 256) sW1[i] = W1[i];
    for (int i = tid; i < LL; i += 256) sTok[i] = xtok[(size_t)b * LL + i];

    // Lane roles: lanes 0..22 own net[:V] (loc), lanes 32..54 own net[V:] (scale).
    const bool activeA = (l < V);
    const bool activeB = (l >= 32 && l < 32 + V);
    const bool active  = activeA || activeB;
    const int  col     = activeA ? l : (activeB ? (l - 32 + V) : 0);

    // h_pre in double: 1024 sequential adds stay within 1 ulp of exact c@W1+b1.
    double h_pre = (double)b1[tid];

    const float bias = active ? b2[col] : 0.f;

    // W2 chunk as 32 float2 pairs: lane holds W2[64w+ii][col], PINNED in VGPR
    // pairs so v_pk_fma_f32 consumes them directly (R7: pk_fma halves matvec
    // issue, -77us). asm "+v" per R4: stops in-loop rematerialization.
    f32x2 wreg2[32];
    #pragma unroll
    for (int ii = 0; ii < 32; ++ii) {
        wreg2[ii].x = active ? W2[(size_t)(64 * w + 2 * ii + 0) * NOUT + col] : 0.f;
        wreg2[ii].y = active ? W2[(size_t)(64 * w + 2 * ii + 1) * NOUT + col] : 0.f;
    }
    #pragma unroll
    for (int ii = 0; ii < 32; ++ii) asm volatile("" : "+v"(wreg2[ii]));

    __syncthreads();

    for (int t = 0; t < LL; ++t) {
        const int tok = sTok[t];   // uniform; issued early, hidden under matvec

        // v = relu(h): lane j of wave w holds v[64w+j]. The wave needs exactly
        // its own lanes' values — broadcast via readlane (SGPR), zero DS ops,
        // zero LDS round-trip latency on the chain.
        const int vbits = __float_as_int(fmaxf((float)h_pre, 0.f));

        // matvec partial: wave w covers rows [64w,64w+64). Uniform SGPR pairs
        // feed pk_fma as the scalar operand; pk(a0+=w0*v0, a1+=w1*v1) is
        // bit-identical to R7's (v*w) pk pairs -> (a0+a1)+(a2+a3) preserved.
        f32x2 A01 = {0.f, 0.f};
        f32x2 A23 = {0.f, 0.f};
        #pragma unroll
        for (int q = 0; q < 16; ++q) {
            f32x2 plo, phi;
            plo.x = __int_as_float(__builtin_amdgcn_readlane(vbits, 4 * q + 0));
            plo.y = __int_as_float(__builtin_amdgcn_readlane(vbits, 4 * q + 1));
            phi.x = __int_as_float(__builtin_amdgcn_readlane(vbits, 4 * q + 2));
            phi.y = __int_as_float(__builtin_amdgcn_readlane(vbits, 4 * q + 3));
            asm("v_pk_fma_f32 %0, %1, %2, %0" : "+v"(A01) : "v"(wreg2[2 * q + 0]), "s"(plo));
            asm("v_pk_fma_f32 %0, %1, %2, %0" : "+v"(A23) : "v"(wreg2[2 * q + 1]), "s"(phi));
        }
        const int p = t & 1;
        sP[p][w][l] = (A01.x + A01.y) + (A23.x + A23.y);   // conflict-free b32 write
        __syncthreads();   // the ONLY barrier per step

        // reduce 4 wave-partials + bias; stride-64 scalar reads pair into
        // ds_read2_b32, conflict-free. Sum order (s0+s1)+(s2+s3) preserved.
        const float* pp = &sP[p][0][l];
        const float p0 = pp[0], p1 = pp[64], p2 = pp[128], p3 = pp[192];
        float net = bias + ((p0 + p1) + (p2 + p3));
        int ib = __float_as_int(net);
        unsigned monoraw = (ib < 0) ? ~(unsigned)ib : ((unsigned)ib ^ 0x80000000u);
        const unsigned orig = active ? monoraw : 0u;  // lane's OWN key, preserved

        // dual 32-lane-half max-reduce on a separate register (VALU DPP only)
        unsigned red = orig;
        DPPMAX(red, 0xB1,  0xF);  // quad_perm xor1
        DPPMAX(red, 0x4E,  0xF);  // quad_perm xor2
        DPPMAX(red, 0x141, 0xF);  // row_half_mirror (combine 4-groups)
        DPPMAX(red, 0x140, 0xF);  // row_mirror      (combine 8-groups)
        DPPMAX(red, 0x142, 0xA);  // row_bcast15 into rows 1,3 (combine rows)
        const unsigned sA = (unsigned)__builtin_amdgcn_readlane((int)red, 16);
        const unsigned sB = (unsigned)__builtin_amdgcn_readlane((int)red, 48);

        // winner = lowest lane whose ORIGINAL key equals its half's max
        // (lowest lane == lowest index == np first-max tie-break)
        const unsigned cmpv = (l < 32) ? sA : sB;
        const unsigned long long bal = __ballot(orig == cmpv);
        const int loc = __builtin_ctzll(bal & 0xFFFFFFFFull);  // lane == col
        const int sc  = __builtin_ctzll(bal >> 32);

        // inverse mod 23 from packed scalar table (no LDS on the chain)
        const unsigned long long tt = (sc < 12) ? INV_T0 : INV_T1;
        const int sh  = 5 * (sc - ((sc >= 12) ? 12 : 0));
        const int inv = (int)((tt >> sh) & 31);

        int m = tok - loc;
        m += (m >> 31) & V;            // (tok - loc) mod 23
        const int k = (m * inv) % V;   // compiler magic-mul for %23

        h_pre += (double)sW1[k * HH + tid];   // stride-1, conflict-free
        if (tid == 0) sK[t] = k;
    }

    __syncthreads();
    float* outb = out + (size_t)b * LL * V;
    for (int t = tid; t < LL; t += 256)
        outb[t * V + sK[t]] = 1.0f;
}

extern "C" void kernel_launch(void* const* d_in, const int* in_sizes, int n_in,
                              void* d_out, int out_size, void* d_ws, size_t ws_size,
                              hipStream_t stream) {
    const int*   xtok = (const int*)d_in[0];
    const float* W1   = (const float*)d_in[1];
    const float* b1   = (const float*)d_in[2];
    const float* W2   = (const float*)d_in[3];
    const float* b2   = (const float*)d_in[4];
    float* out = (float*)d_out;

    // d_out poisoned 0xAA pre-launch: zero it, kernel scatters the 1.0s
    hipMemsetAsync(out, 0, (size_t)out_size * sizeof(float), stream);
    daf_kernel<<<BB, 256, 0, stream>>>(xtok, W1, b1, W2, b2, out);
}

// Round 10
// 687.624 us; speedup vs baseline: 1.2120x; 1.2120x over previous
//
#include <hip/hip_runtime.h>
#include <math.h>

#define V 23
#define HH 256
#define BB 512
#define LL 1024
#define NOUT 46  // 2V

typedef float f32x2 __attribute__((ext_vector_type(2)));
typedef float f32x4 __attribute__((ext_vector_type(4)));

// Multiplicative inverses mod 23, packed 5 bits/entry into two u64 scalars
// (entries 0..11 in T0, 12..22 in T1) so the inverse lookup is pure SALU.
constexpr unsigned long long packInv(int lo) {
    const int inv[23] = {0,1,12,8,6,14,4,10,3,18,7,21,2,16,5,20,13,19,9,17,15,11,22};
    unsigned long long t = 0;
    for (int i = 0; i < 12; ++i) {
        int idx = lo + i;
        if (idx < 23) t |= (unsigned long long)inv[idx] << (5 * i);
    }
    return t;
}
constexpr unsigned long long INV_T0 = packInv(0);
constexpr unsigned long long INV_T1 = packInv(12);

// VALU max-reduce step via DPP (no DS pipe, ~8 cy vs ~120 cy ds_swizzle)
#define DPPMAX(v, ctrl, rmask)                                                  \
    do {                                                                        \
        unsigned _t = (unsigned)__builtin_amdgcn_update_dpp(                    \
            (int)(v), (int)(v), (ctrl), (rmask), 0xF, false);                   \
        (v) = ((v) > _t) ? (v) : _t;                                            \
    } while (0)

// R13: R7 base restored EXACTLY (674us champion; R12's readlane-pk regressed
// to 802 — uniform-address ds_read_b128 is the cheapest intra-wave broadcast,
// proven 3x now). Two chain-shavings, both pipe-neutral and pressure-neutral:
// (1) sP reduce via ONE ds_read_b128 from a transposed XOR-swizzled layout
//     sPT[p][lane][wave^((lane>>3)&3)] — write 2-way-bank-free, read is
//     minimum-time b128. XOR perms preserve the pair partition {{0,1},{2,3}},
//     so (ps.x+ps.y)+(ps.z+ps.w) == (s0+s1)+(s2+s3) BIT-EXACTLY, static idx.
// (2) argmax tail: drop the 5th dependent DPP (row_bcast15); after 4 DPPs
//     each 16-row has its max -> 4 independent readlanes + 2 s_max off-chain.
__global__ __launch_bounds__(256, 2)
void daf_kernel(const int* __restrict__ xtok,
                const float* __restrict__ W1,
                const float* __restrict__ b1,
                const float* __restrict__ W2,
                const float* __restrict__ b2,
                float* __restrict__ out)
{
    __shared__ float sW1[V * HH];     // W1 rows for the h-update
    __shared__ float sV[HH];          // relu(h); wave w only touches [64w,64w+64)
    __shared__ float sPT[2][64][4];   // partials [parity][lane][slot], XOR-swizzled
    __shared__ int   sTok[LL];
    __shared__ int   sK[LL];          // emitted symbols; flushed to global at end

    const int tid = threadIdx.x;
    const int w   = tid >> 6;
    const int l   = tid & 63;
    const int b   = blockIdx.x;

    for (int i = tid; i < V * HH; i += 256) sW1[i] = W1[i];
    for (int i = tid; i < LL; i += 256) sTok[i] = xtok[(size_t)b * LL + i];

    // Lane roles: lanes 0..22 own net[:V] (loc), lanes 32..54 own net[V:] (scale).
    const bool activeA = (l < V);
    const bool activeB = (l >= 32 && l < 32 + V);
    const bool active  = activeA || activeB;
    const int  col     = activeA ? l : (activeB ? (l - 32 + V) : 0);

    // XOR-swizzled slot for this wave's partial in row l (bank-spread: the 8
    // lanes sharing a 4-bank group get 4 distinct slots -> 2-way = free).
    const int slot = w ^ ((l >> 3) & 3);

    // h_pre in double: 1024 sequential adds stay within 1 ulp of exact c@W1+b1.
    double h_pre = (double)b1[tid];

    const float bias = active ? b2[col] : 0.f;

    // W2 chunk as 32 float2 pairs: lane holds W2[64w+ii][col], PINNED in VGPR
    // pairs so v_pk_fma_f32 consumes them directly (R7: pk_fma halves matvec
    // issue, -77us). asm "+v" per R4: stops in-loop rematerialization.
    f32x2 wreg2[32];
    #pragma unroll
    for (int ii = 0; ii < 32; ++ii) {
        wreg2[ii].x = active ? W2[(size_t)(64 * w + 2 * ii + 0) * NOUT + col] : 0.f;
        wreg2[ii].y = active ? W2[(size_t)(64 * w + 2 * ii + 1) * NOUT + col] : 0.f;
    }
    #pragma unroll
    for (int ii = 0; ii < 32; ++ii) asm volatile("" : "+v"(wreg2[ii]));

    __syncthreads();

    for (int t = 0; t < LL; ++t) {
        const int tok = sTok[t];   // uniform; issued early, hidden under matvec

        // publish v = relu(h); consumed only by this wave's own matvec chunk
        // (wave-internal: in-order DS per wave, no barrier needed)
        float v = fmaxf((float)h_pre, 0.f);
        sV[tid] = v;

        // matvec partial: wave w covers rows [64w,64w+64). Uniform-address
        // b128 reads broadcast (cheap); v_pk_fma_f32 does 2 MACs/instr:
        // pk(a0+=vx*w0, a1+=vy*w1) is bit-identical to the two scalar fmafs,
        // so the (a0+a1)+(a2+a3) order is preserved exactly.
        const f32x4* pv = (const f32x4*)(sV + 64 * w);
        f32x2 A01 = {0.f, 0.f};
        f32x2 A23 = {0.f, 0.f};
        #pragma unroll
        for (int q = 0; q < 16; ++q) {
            f32x4 vv = pv[q];
            f32x2 vlo = __builtin_shufflevector(vv, vv, 0, 1);
            f32x2 vhi = __builtin_shufflevector(vv, vv, 2, 3);
            asm("v_pk_fma_f32 %0, %1, %2, %0" : "+v"(A01) : "v"(vlo), "v"(wreg2[2 * q + 0]));
            asm("v_pk_fma_f32 %0, %1, %2, %0" : "+v"(A23) : "v"(vhi), "v"(wreg2[2 * q + 1]));
        }
        const int p = t & 1;
        sPT[p][l][slot] = (A01.x + A01.y) + (A23.x + A23.y);  // 2-way free write
        __syncthreads();   // the ONLY barrier per step

        // reduce 4 wave-partials + bias with ONE b128 read. Position j of row
        // l holds s_{j^c} (c = (l>>3)&3); pairing {{0,1},{2,3}} is XOR-stable,
        // so (ps.x+ps.y)+(ps.z+ps.w) == (s0+s1)+(s2+s3) bit-exactly.
        const f32x4 ps = *(const f32x4*)&sPT[p][l][0];
        float net = bias + ((ps.x + ps.y) + (ps.z + ps.w));
        int ib = __float_as_int(net);
        unsigned monoraw = (ib < 0) ? ~(unsigned)ib : ((unsigned)ib ^ 0x80000000u);
        const unsigned orig = active ? monoraw : 0u;  // lane's OWN key, preserved

        // 16-lane-row max-reduce: 4 dependent DPP steps, then combine rows
        // with independent readlanes + scalar max (off the dependent chain).
        unsigned red = orig;
        DPPMAX(red, 0xB1,  0xF);  // quad_perm xor1
        DPPMAX(red, 0x4E,  0xF);  // quad_perm xor2
        DPPMAX(red, 0x141, 0xF);  // row_half_mirror (combine 4-groups)
        DPPMAX(red, 0x140, 0xF);  // row_mirror      (combine 8-groups)
        const unsigned r0  = (unsigned)__builtin_amdgcn_readlane((int)red, 0);
        const unsigned r16 = (unsigned)__builtin_amdgcn_readlane((int)red, 16);
        const unsigned r32 = (unsigned)__builtin_amdgcn_readlane((int)red, 32);
        const unsigned r48 = (unsigned)__builtin_amdgcn_readlane((int)red, 48);
        const unsigned sA = (r0 > r16) ? r0 : r16;
        const unsigned sB = (r32 > r48) ? r32 : r48;

        // winner = lowest lane whose ORIGINAL key equals its half's max
        // (lowest lane == lowest index == np first-max tie-break)
        const unsigned cmpv = (l < 32) ? sA : sB;
        const unsigned long long bal = __ballot(orig == cmpv);
        const int loc = __builtin_ctzll(bal & 0xFFFFFFFFull);  // lane == col
        const int sc  = __builtin_ctzll(bal >> 32);

        // inverse mod 23 from packed scalar table (no LDS on the chain)
        const unsigned long long tt = (sc < 12) ? INV_T0 : INV_T1;
        const int sh  = 5 * (sc - ((sc >= 12) ? 12 : 0));
        const int inv = (int)((tt >> sh) & 31);

        int m = tok - loc;
        m += (m >> 31) & V;            // (tok - loc) mod 23
        const int k = (m * inv) % V;   // compiler magic-mul for %23

        h_pre += (double)sW1[k * HH + tid];   // stride-1, conflict-free
        if (tid == 0) sK[t] = k;
    }

    __syncthreads();
    float* outb = out + (size_t)b * LL * V;
    for (int t = tid; t < LL; t += 256)
        outb[t * V + sK[t]] = 1.0f;
}

extern "C" void kernel_launch(void* const* d_in, const int* in_sizes, int n_in,
                              void* d_out, int out_size, void* d_ws, size_t ws_size,
                              hipStream_t stream) {
    const int*   xtok = (const int*)d_in[0];
    const float* W1   = (const float*)d_in[1];
    const float* b1   = (const float*)d_in[2];
    const float* W2   = (const float*)d_in[3];
    const float* b2   = (const float*)d_in[4];
    float* out = (float*)d_out;

    // d_out poisoned 0xAA pre-launch: zero it, kernel scatters the 1.0s
    hipMemsetAsync(out, 0, (size_t)out_size * sizeof(float), stream);
    daf_kernel<<<BB, 256, 0, stream>>>(xtok, W1, b1, W2, b2, out);
}